// Round 1
// baseline (477.530 us; speedup 1.0000x reference)
//
#include <hip/hip_runtime.h>

// Problem constants (B,C,H,W = 32,64,128,128)
static constexpr int Cc  = 64;
static constexpr int HWc = 16384;   // 128*128
static constexpr int Bc  = 32;

// ---------------------------------------------------------------------------
// Identity: A[b] = -0.5*theta (independent of x) because
//   T[i,j] = sigmoid(w_i - w_j) - 1  and  sigmoid(d)+sigmoid(-d) = 1
// so out[b,n,:] = W_lin @ relu(-0.5 * theta @ x[b,:,n]) + b_lin.
// Pooling pass is dead code; x is read exactly once.
// ---------------------------------------------------------------------------

// Tiny prep: W2[i*64+c] = W_lin[c*64+i]  (transpose so the inner unrolled loop
// reads contiguous, wave-uniform addresses -> s_load_dwordx* friendly).
__global__ void prep_transpose(const float* __restrict__ Wl, float* __restrict__ W2) {
    int t = blockIdx.x * 256 + threadIdx.x;      // t = i*64 + c
    if (t < Cc * Cc) {
        int i = t >> 6, c = t & 63;
        W2[t] = Wl[c * Cc + i];
    }
}

__global__ __launch_bounds__(256) void fused_graph_conv(
    const float* __restrict__ x,      // [B, C, HW]
    const float* __restrict__ theta,  // [C, C] row-major (i, c)
    const float* __restrict__ W2,     // [C, C] transposed W_lin: W2[i][c] = W_lin[c][i]
    const float* __restrict__ blin,   // [C]
    float* __restrict__ out)          // [B, HW, C] flat
{
    const int g = blockIdx.x * 256 + threadIdx.x;   // global pixel id, 0..B*HW-1
    const int b = g >> 14;                          // HW = 16384 = 2^14
    const int n = g & (HWc - 1);

    // ---- load this pixel's channel vector (coalesced: lane -> consecutive n)
    const float* xp = x + (size_t)b * Cc * HWc + n;
    float xv[Cc];
#pragma unroll
    for (int c = 0; c < Cc; ++c) xv[c] = xp[(size_t)c * HWc];

    // ---- init y with bias (wave-uniform scalar loads)
    float y[Cc];
#pragma unroll
    for (int c = 0; c < Cc; ++c) y[c] = blin[c];

    // ---- fused double matvec: for each hidden channel i,
    //      h_i = relu(-0.5 * <theta[i,:], xv>) ; y[:] += W2[i,:] * h_i
    //      theta/W2 rows are wave-uniform -> scalar loads, FMAs vs SGPR.
#pragma unroll 2
    for (int i = 0; i < Cc; ++i) {
        // 4-way split accumulators for ILP (avoid one serial 64-FMA chain)
        float a0 = 0.f, a1 = 0.f, a2 = 0.f, a3 = 0.f;
#pragma unroll
        for (int c = 0; c < Cc; c += 4) {
            a0 = fmaf(theta[i * Cc + c + 0], xv[c + 0], a0);
            a1 = fmaf(theta[i * Cc + c + 1], xv[c + 1], a1);
            a2 = fmaf(theta[i * Cc + c + 2], xv[c + 2], a2);
            a3 = fmaf(theta[i * Cc + c + 3], xv[c + 3], a3);
        }
        const float acc = (a0 + a1) + (a2 + a3);
        const float h = fmaxf(-0.5f * acc, 0.f);
#pragma unroll
        for (int c = 0; c < Cc; ++c) y[c] = fmaf(W2[i * Cc + c], h, y[c]);
    }

    // ---- store: 64 contiguous floats per pixel (16 x float4 per lane)
    float4* op = (float4*)(out + (size_t)g * Cc);
#pragma unroll
    for (int q = 0; q < Cc / 4; ++q)
        op[q] = make_float4(y[4 * q + 0], y[4 * q + 1], y[4 * q + 2], y[4 * q + 3]);
}

extern "C" void kernel_launch(void* const* d_in, const int* in_sizes, int n_in,
                              void* d_out, int out_size, void* d_ws, size_t ws_size,
                              hipStream_t stream) {
    const float* x     = (const float*)d_in[0];   // [32,64,128,128]
    const float* theta = (const float*)d_in[1];   // [64,64]
    const float* W_lin = (const float*)d_in[2];   // [64,64]
    const float* b_lin = (const float*)d_in[3];   // [64]
    float* out = (float*)d_out;

    float* W2 = (float*)d_ws;                     // 4096 floats scratch

    prep_transpose<<<(Cc * Cc + 255) / 256, 256, 0, stream>>>(W_lin, W2);

    const int total_pixels = Bc * HWc;            // 524288
    fused_graph_conv<<<total_pixels / 256, 256, 0, stream>>>(x, theta, W2, b_lin, out);
}

// Round 2
// 239.814 us; speedup vs baseline: 1.9913x; 1.9913x over previous
//
#include <hip/hip_runtime.h>

// Problem constants (B,C,H,W = 32,64,128,128)
static constexpr int Cc  = 64;
static constexpr int HWc = 16384;   // 128*128
static constexpr int Bc  = 32;
static constexpr int NT  = 256;     // pixels per block (4 waves x 64 pixels)

// ---------------------------------------------------------------------------
// Identity (verified round 1, absmax 7.8e-3): sigmoid(d)+sigmoid(-d)=1 makes
// A[b] = -0.5*theta exactly, so out[b,n,:] = W_lin @ relu(-0.5*theta @ x[b,:,n]) + b_lin.
// Round 2: MFMA formulation. Per 256-pixel tile:
//   GEMM1: P[n,i] = relu( sum_c xT[n,c] * M1[i,c] ),  M1 = -0.5*theta (f16)
//   GEMM2: out[n,c] = sum_i P[n,i] * W_lin[c,i] + b_lin[c]
// mfma_f32_16x16x32_f16 layouts (HW-verified, dtype-independent):
//   A[m=lane&15][k=quad*8+j]   B[col=lane&15][k=quad*8+j]   C/D: col=lane&15,row=quad*4+reg
// ---------------------------------------------------------------------------

typedef _Float16 v8h __attribute__((ext_vector_type(8)));
typedef float    v4f __attribute__((ext_vector_type(4)));

union FragU { uint32_t u[4]; v8h h; };

__device__ inline uint32_t packf2(float lo, float hi) {
  union { _Float16 h[2]; uint32_t u; } r;
  r.h[0] = (_Float16)lo; r.h[1] = (_Float16)hi;
  return r.u;
}

// Prep: f16 weights. M1h = -0.5*theta (row-major [i][c]); Wh = W_lin (row-major [c][i]).
__global__ void prep_weights(const float* __restrict__ theta,
                             const float* __restrict__ Wlin,
                             _Float16* __restrict__ M1h,
                             _Float16* __restrict__ Wh) {
  int t = blockIdx.x * 256 + threadIdx.x;
  if (t < Cc * Cc) {
    M1h[t] = (_Float16)(-0.5f * theta[t]);
    Wh[t]  = (_Float16)(Wlin[t]);
  }
}

__global__ __launch_bounds__(256) void fused_mfma(
    const float* __restrict__ x,      // [B, C, HW]
    const _Float16* __restrict__ M1h, // [64][64]
    const _Float16* __restrict__ Wh,  // [64][64]
    const float* __restrict__ blin,   // [64]
    float* __restrict__ out)          // [B, HW, C]
{
  // xp: x tile as f16x2 channel-pairs, xp[p][n] = (x[2p][n], x[2p+1][n]).
  //     row stride 260 dwords: 16B-aligned rows (1040B), bank stride 4 -> 2-way (free).
  // p2: per-wave P tile [64 n][64 i] f16, row stride 72 (144B, 16B-aligned).
  // p2 aliases xp (union) -> barrier between last xp read and first p2 write.
  __shared__ __align__(16) union {
    uint32_t xp[32][260];             // 33280 B
    _Float16 p2[4][64][72];           // 36864 B
  } lds;

  const int tid = threadIdx.x;
  const int b   = blockIdx.x >> 6;          // 64 tiles per batch
  const int n0  = (blockIdx.x & 63) * NT;

  // ---- stage x tile: 2048 uint4 chunks, 8 per thread, coalesced float4 reads
  const float* xb = x + (size_t)b * Cc * HWc + n0;
#pragma unroll
  for (int rep = 0; rep < 8; ++rep) {
    const int chunk = rep * 256 + tid;
    const int p   = chunk >> 6;               // pair row 0..31
    const int col = (chunk & 63) * 4;         // pixel col, x4
    const float4 e = *(const float4*)(xb + (size_t)(2 * p)     * HWc + col);
    const float4 o = *(const float4*)(xb + (size_t)(2 * p + 1) * HWc + col);
    uint4 w;
    w.x = packf2(e.x, o.x); w.y = packf2(e.y, o.y);
    w.z = packf2(e.z, o.z); w.w = packf2(e.w, o.w);
    *(uint4*)&lds.xp[p][col] = w;             // ds_write_b128
  }
  __syncthreads();

  const int wv   = tid >> 6;        // wave 0..3, owns pixels [wv*64, wv*64+64)
  const int lq   = tid & 15;
  const int quad = (tid & 63) >> 4;
  const int nw   = wv * 64;

  // ---- A1 frags (x^T) from LDS: a1[mt][kt], u32 reg r = channel-pair kt*16+quad*4+r
  FragU a1[4][2];
#pragma unroll
  for (int mt = 0; mt < 4; ++mt)
#pragma unroll
    for (int kt = 0; kt < 2; ++kt)
#pragma unroll
      for (int r = 0; r < 4; ++r)
        a1[mt][kt].u[r] = lds.xp[kt * 16 + quad * 4 + r][nw + mt * 16 + lq];

  // ---- B1 frags (M1, row-major = B-layout): 16B per lane, L2-resident
  const v8h* M1v = (const v8h*)M1h;
  v8h b1[4][2];
#pragma unroll
  for (int it = 0; it < 4; ++it)
#pragma unroll
    for (int kt = 0; kt < 2; ++kt)
      b1[it][kt] = M1v[(it * 16 + lq) * 8 + kt * 4 + quad];

  // ---- GEMM1: acc1[mt][it] = xT @ M1^T   (n x i)
  v4f acc1[4][4];
#pragma unroll
  for (int mt = 0; mt < 4; ++mt)
#pragma unroll
    for (int it = 0; it < 4; ++it) {
      v4f a = {0.f, 0.f, 0.f, 0.f};
#pragma unroll
      for (int kt = 0; kt < 2; ++kt)
        a = __builtin_amdgcn_mfma_f32_16x16x32_f16(a1[mt][kt].h, b1[it][kt], a, 0, 0, 0);
      acc1[mt][it] = a;
    }

  __syncthreads();   // all xp reads complete before p2 (aliased) is written

  // ---- ReLU + f16 + store P in [n][i] rows (C/D layout -> A layout via LDS)
#pragma unroll
  for (int mt = 0; mt < 4; ++mt)
#pragma unroll
    for (int it = 0; it < 4; ++it)
#pragma unroll
      for (int r = 0; r < 4; ++r)
        lds.p2[wv][mt * 16 + quad * 4 + r][it * 16 + lq] =
            (_Float16)fmaxf(acc1[mt][it][r], 0.f);
  __syncthreads();   // cheap safety; dep is actually in-wave only

  // ---- B2 frags (W_lin row-major [c][i] = exactly B-layout) + bias
  const v8h* Whv = (const v8h*)Wh;
  v8h b2[4][2];
#pragma unroll
  for (int ct = 0; ct < 4; ++ct)
#pragma unroll
    for (int kt = 0; kt < 2; ++kt)
      b2[ct][kt] = Whv[(ct * 16 + lq) * 8 + kt * 4 + quad];

  float bias[4];
#pragma unroll
  for (int ct = 0; ct < 4; ++ct) bias[ct] = blin[ct * 16 + lq];

  // ---- GEMM2: out[n][c] = P @ W_lin^T + b
  const size_t outbase = ((size_t)b * HWc + n0 + nw) * Cc;
#pragma unroll
  for (int mt = 0; mt < 4; ++mt) {
    FragU a2[2];
#pragma unroll
    for (int kt = 0; kt < 2; ++kt)
      a2[kt].h = *(const v8h*)&lds.p2[wv][mt * 16 + lq][kt * 32 + quad * 8];
#pragma unroll
    for (int ct = 0; ct < 4; ++ct) {
      v4f a = {bias[ct], bias[ct], bias[ct], bias[ct]};
#pragma unroll
      for (int kt = 0; kt < 2; ++kt)
        a = __builtin_amdgcn_mfma_f32_16x16x32_f16(a2[kt].h, b2[ct][kt], a, 0, 0, 0);
#pragma unroll
      for (int r = 0; r < 4; ++r)
        out[outbase + (size_t)(mt * 16 + quad * 4 + r) * Cc + ct * 16 + lq] = a[r];
    }
  }
}

extern "C" void kernel_launch(void* const* d_in, const int* in_sizes, int n_in,
                              void* d_out, int out_size, void* d_ws, size_t ws_size,
                              hipStream_t stream) {
  const float* x     = (const float*)d_in[0];
  const float* theta = (const float*)d_in[1];
  const float* W_lin = (const float*)d_in[2];
  const float* b_lin = (const float*)d_in[3];
  float* out = (float*)d_out;

  _Float16* M1h = (_Float16*)d_ws;
  _Float16* Wh  = M1h + Cc * Cc;

  prep_weights<<<(Cc * Cc + 255) / 256, 256, 0, stream>>>(theta, W_lin, M1h, Wh);

  const int nblocks = Bc * HWc / NT;   // 2048
  fused_mfma<<<nblocks, 256, 0, stream>>>(x, M1h, Wh, b_lin, out);
}